// Round 4
// baseline (236.067 us; speedup 1.0000x reference)
//
#include <hip/hip_runtime.h>
#include <cmath>
#include <stdint.h>

#define HE 361
#define WE 720
#define LL 37
#define HM 180
#define WM 360
#define KK 32
#define NPTS (HM * WM)
#define EPSF 1e-8f
#define PTSB 8                      // model points per block; 360 % 8 == 0
#define NC 9                        // corner columns cached per block (cols ix0..ix0+8)
#define NSEG (2 * NC * 5)           // 90 segments of 37 floats
#define TOTF (NSEG * LL)            // 3330 floats
#define NIT ((TOTF + 255) / 256)    // 14 load iterations
#define LDSF (NIT * 256)            // 3584 floats LDS (incl. slack)

// out layout: out3d [HM*WM*KK*5] | p_model [HM*WM*KK] | ps_o [HM*WM]
#define OFF1 ((size_t)HM * WM * KK * 5)
#define OFF2 (OFF1 + (size_t)HM * WM * KK)

// ws layout (float units):
#define WS_IY    0
#define WS_TY    180
#define WS_IX    360
#define WS_TX    720
#define WS_LOGPE 1080

__device__ __forceinline__ int upper_bound_g(const float* a, int n, float v) {
    int lo = 0, hi = n;
    while (lo < hi) {
        int m = (lo + hi) >> 1;
        if (a[m] <= v) lo = m + 1; else hi = m;
    }
    return lo;  // searchsorted side='right'
}

__global__ void precompute_kernel(const float* __restrict__ era5_lat,
                                  const float* __restrict__ era5_lon,
                                  const float* __restrict__ model_lat,
                                  const float* __restrict__ model_lon,
                                  const float* __restrict__ p_levels,
                                  int* __restrict__ ws_iy, float* __restrict__ ws_ty,
                                  int* __restrict__ ws_ix, float* __restrict__ ws_tx,
                                  float* __restrict__ ws_logpe) {
    int t = blockIdx.x * blockDim.x + threadIdx.x;
    if (t < HM) {
        float v = model_lat[t];
        int i = upper_bound_g(era5_lat, HE, v) - 1;
        if (i < 0) i = 0;
        if (i > HE - 2) i = HE - 2;
        ws_iy[t] = i;
        ws_ty[t] = (v - era5_lat[i]) / (era5_lat[i + 1] - era5_lat[i]);
    } else if (t < HM + WM) {
        int j = t - HM;
        float v = model_lon[j];
        int i = upper_bound_g(era5_lon, WE, v) - 1;
        if (i < 0) i = 0;
        if (i > WE - 2) i = WE - 2;
        ws_ix[j] = i;
        ws_tx[j] = (v - era5_lon[i]) / (era5_lon[i + 1] - era5_lon[i]);
    } else if (t < HM + WM + LL) {
        int k = t - HM - WM;
        ws_logpe[k] = logf(p_levels[k] + EPSF);
    }
}

// Block = 8 consecutive model points of one row.
// Phase 1: async global_load_lds of the 18 unique corner columns (2 rows x 9 cols x 185).
//   LDS layout: s_cols[((r*NC + c)*5 + var)*37 + l], flat index == load index.
// Phase 2: thread (pt_local, k) does bilinear(4 corners) at levels i,i+1 + vertical lerp.
__global__ void __launch_bounds__(256)
fused_kernel(const float* __restrict__ u, const float* __restrict__ v,
             const float* __restrict__ w, const float* __restrict__ T,
             const float* __restrict__ q, const float* __restrict__ ps,
             const float* __restrict__ p_levels,
             const float* __restrict__ a_k, const float* __restrict__ b_k,
             const int* __restrict__ ws_iy, const float* __restrict__ ws_ty,
             const int* __restrict__ ws_ix, const float* __restrict__ ws_tx,
             const float* __restrict__ ws_logpe,
             float* __restrict__ out) {
    __shared__ float s_cols[LDSF];
    __shared__ float s_psm[PTSB];
    __shared__ float s_plev[LL];
    __shared__ float s_logpe[LL];
    __shared__ float s_ak[KK];
    __shared__ float s_bk[KK];

    const int tid = threadIdx.x;
    const int pt0 = blockIdx.x * PTSB;
    const int y   = pt0 / WM;          // whole block in one row
    const int x0  = pt0 - y * WM;

    const int   iy    = ws_iy[y];
    const int   colLo = ws_ix[x0];

    // ---- Phase 1: issue all async loads first (14 in flight per thread) ----
    const int wavebase = __builtin_amdgcn_readfirstlane(tid & ~63);
#pragma unroll
    for (int it = 0; it < NIT; it++) {
        int idx = it * 256 + tid;
        int idc = (idx < TOTF) ? idx : (TOTF - 1);
        int seg = idc / LL;
        int l   = idc - seg * LL;
        int r   = seg / (NC * 5);
        int rem = seg - r * (NC * 5);
        int c   = rem / 5;
        int var = rem - c * 5;
        int col = colLo + c;
        if (col > WE - 1) col = WE - 1;
        const float* sp = (var == 0) ? u : (var == 1) ? v : (var == 2) ? w
                        : (var == 3) ? T : q;
        const float* ga = sp + ((size_t)(iy + r) * WE + col) * LL + l;
        __builtin_amdgcn_global_load_lds(
            (const __attribute__((address_space(1))) uint32_t*)ga,
            (__attribute__((address_space(3))) uint32_t*)&s_cols[it * 256 + wavebase],
            4, 0, 0);
    }

    // ---- constants + ps while loads are in flight ----
    if (tid < LL) {
        s_plev[tid]  = p_levels[tid];
        s_logpe[tid] = ws_logpe[tid];
    } else if (tid >= 64 && tid < 64 + KK) {
        s_ak[tid - 64] = a_k[tid - 64];
        s_bk[tid - 64] = b_k[tid - 64];
    }

    const int pt_local = tid >> 5;      // 0..7
    const int grp      = tid & 31;      // 0..31 (= k in phase 2)
    const int pt = pt0 + pt_local;
    const int x  = x0 + pt_local;

    const float ty = ws_ty[y];
    const float tx = ws_tx[x];
    const int   ixp = ws_ix[x];
    const float omty = 1.0f - ty;
    const float omtx = 1.0f - tx;

    if (grp == 0) {
        const size_t b00 = (size_t)iy * WE + ixp;
        const float p00 = ps[b00], p01 = ps[b00 + 1];
        const float p10 = ps[b00 + WE], p11 = ps[b00 + WE + 1];
        const float ps_m = omty * (omtx * p00 + tx * p01) + ty * (omtx * p10 + tx * p11);
        s_psm[pt_local] = ps_m;
        out[OFF2 + pt] = fminf(fmaxf(ps_m, 30000.0f), 110000.0f);
    }

    __syncthreads();   // drains the global_load_lds queue + s_psm

    // ---- Phase 2: vertical interp per (pt_local, k) ----
    const int k = grp;
    const float ps_m = s_psm[pt_local];

    int nvalid = 0;
#pragma unroll
    for (int l = 0; l < LL; l++) nvalid += (s_plev[l] <= ps_m) ? 1 : 0;
    int maxi = nvalid - 2;
    if (maxi < 0) maxi = 0;

    const float pm = s_ak[k] + s_bk[k] * ps_m;
    out[OFF1 + (size_t)pt * KK + k] = pm;

    const float lpm = logf(pm + EPSF);
    int lo = 0, hi = LL;
    while (lo < hi) {
        int m = (lo + hi) >> 1;
        if (s_logpe[m] <= lpm) lo = m + 1; else hi = m;
    }
    int i = lo - 1;
    if (i < 0) i = 0;
    if (i > maxi) i = maxi;
    const float t = (lpm - s_logpe[i]) / (s_logpe[i + 1] - s_logpe[i]);

    const bool invalid = (nvalid < 2);
    const size_t obase = (size_t)pt * (KK * 5) + k * 5;

    const int cpt = ixp - colLo;
    if (cpt >= 0 && cpt <= NC - 2) {
        // fast path: corners live in LDS
        const int o00 = (cpt * 5) * LL;
        const int o01 = ((cpt + 1) * 5) * LL;
        const int o10 = ((NC + cpt) * 5) * LL;
        const int o11 = ((NC + cpt + 1) * 5) * LL;
#pragma unroll
        for (int var = 0; var < 5; var++) {
            const int vb = var * LL + i;
            const float a0 = s_cols[o00 + vb],     b0 = s_cols[o01 + vb];
            const float c0 = s_cols[o10 + vb],     d0 = s_cols[o11 + vb];
            const float a1 = s_cols[o00 + vb + 1], b1 = s_cols[o01 + vb + 1];
            const float c1 = s_cols[o10 + vb + 1], d1 = s_cols[o11 + vb + 1];
            const float g0 = omty * (omtx * a0 + tx * b0) + ty * (omtx * c0 + tx * d0);
            const float g1 = omty * (omtx * a1 + tx * b1) + ty * (omtx * c1 + tx * d1);
            float o = g0 + t * (g1 - g0);
            if (invalid) o = 0.0f;                       // zero BEFORE clip (matches ref)
            if (var == 3) o = fminf(fmaxf(o, 150.0f), 350.0f);
            if (var == 4) o = fminf(fmaxf(o, 0.0f), 0.05f);
            out[obase + var] = o;
        }
    } else {
        // slow path (never taken on this grid): corners straight from global
        const size_t c00 = ((size_t)iy * WE + ixp) * LL;
        const size_t c01 = c00 + LL;
        const size_t c10 = c00 + (size_t)WE * LL;
        const size_t c11 = c10 + LL;
#pragma unroll
        for (int var = 0; var < 5; var++) {
            const float* sp = (var == 0) ? u : (var == 1) ? v : (var == 2) ? w
                            : (var == 3) ? T : q;
            const float a0 = sp[c00 + i], b0 = sp[c01 + i];
            const float c0 = sp[c10 + i], d0 = sp[c11 + i];
            const float a1 = sp[c00 + i + 1], b1 = sp[c01 + i + 1];
            const float c1 = sp[c10 + i + 1], d1 = sp[c11 + i + 1];
            const float g0 = omty * (omtx * a0 + tx * b0) + ty * (omtx * c0 + tx * d0);
            const float g1 = omty * (omtx * a1 + tx * b1) + ty * (omtx * c1 + tx * d1);
            float o = g0 + t * (g1 - g0);
            if (invalid) o = 0.0f;
            if (var == 3) o = fminf(fmaxf(o, 150.0f), 350.0f);
            if (var == 4) o = fminf(fmaxf(o, 0.0f), 0.05f);
            out[obase + var] = o;
        }
    }
}

extern "C" void kernel_launch(void* const* d_in, const int* in_sizes, int n_in,
                              void* d_out, int out_size, void* d_ws, size_t ws_size,
                              hipStream_t stream) {
    const float* u         = (const float*)d_in[0];
    const float* v         = (const float*)d_in[1];
    const float* w         = (const float*)d_in[2];
    const float* T         = (const float*)d_in[3];
    const float* q         = (const float*)d_in[4];
    const float* ps        = (const float*)d_in[5];
    const float* era5_lat  = (const float*)d_in[6];
    const float* era5_lon  = (const float*)d_in[7];
    const float* model_lat = (const float*)d_in[8];
    const float* model_lon = (const float*)d_in[9];
    const float* p_levels  = (const float*)d_in[10];
    const float* a_k       = (const float*)d_in[11];
    const float* b_k       = (const float*)d_in[12];

    float* wsf = (float*)d_ws;
    int*   ws_iy    = (int*)(wsf + WS_IY);
    float* ws_ty    = wsf + WS_TY;
    int*   ws_ix    = (int*)(wsf + WS_IX);
    float* ws_tx    = wsf + WS_TX;
    float* ws_logpe = wsf + WS_LOGPE;

    float* out = (float*)d_out;

    precompute_kernel<<<3, 256, 0, stream>>>(era5_lat, era5_lon, model_lat, model_lon,
                                             p_levels, ws_iy, ws_ty, ws_ix, ws_tx,
                                             ws_logpe);

    const int blocks = NPTS / PTSB;   // 8100
    fused_kernel<<<blocks, 256, 0, stream>>>(u, v, w, T, q, ps, p_levels, a_k, b_k,
                                             ws_iy, ws_ty, ws_ix, ws_tx, ws_logpe, out);
}

// Round 5
// 232.494 us; speedup vs baseline: 1.0154x; 1.0154x over previous
//
#include <hip/hip_runtime.h>
#include <cmath>

#define HE 361
#define WE 720
#define LL 37
#define HM 180
#define WM 360
#define KK 32
#define NPTS (HM * WM)
#define EPSF 1e-8f
#define PTSB 8   // model points per block; 360 % 8 == 0 -> block never crosses a row

// out layout: out3d [HM*WM*KK*5] | p_model [HM*WM*KK] | ps_o [HM*WM]
#define OFF1 ((size_t)HM * WM * KK * 5)
#define OFF2 (OFF1 + (size_t)HM * WM * KK)

// ws layout (float units):
#define WS_IY    0
#define WS_TY    180
#define WS_IX    360
#define WS_TX    720
#define WS_LOGPE 1080

__device__ __forceinline__ int upper_bound_g(const float* a, int n, float v) {
    int lo = 0, hi = n;
    while (lo < hi) {
        int m = (lo + hi) >> 1;
        if (a[m] <= v) lo = m + 1; else hi = m;
    }
    return lo;  // searchsorted side='right'
}

__global__ void precompute_kernel(const float* __restrict__ era5_lat,
                                  const float* __restrict__ era5_lon,
                                  const float* __restrict__ model_lat,
                                  const float* __restrict__ model_lon,
                                  const float* __restrict__ p_levels,
                                  int* __restrict__ ws_iy, float* __restrict__ ws_ty,
                                  int* __restrict__ ws_ix, float* __restrict__ ws_tx,
                                  float* __restrict__ ws_logpe) {
    int t = blockIdx.x * blockDim.x + threadIdx.x;
    if (t < HM) {
        float v = model_lat[t];
        int i = upper_bound_g(era5_lat, HE, v) - 1;
        if (i < 0) i = 0;
        if (i > HE - 2) i = HE - 2;
        ws_iy[t] = i;
        ws_ty[t] = (v - era5_lat[i]) / (era5_lat[i + 1] - era5_lat[i]);
    } else if (t < HM + WM) {
        int j = t - HM;
        float v = model_lon[j];
        int i = upper_bound_g(era5_lon, WE, v) - 1;
        if (i < 0) i = 0;
        if (i > WE - 2) i = WE - 2;
        ws_ix[j] = i;
        ws_tx[j] = (v - era5_lon[i]) / (era5_lon[i + 1] - era5_lon[i]);
    } else if (t < HM + WM + LL) {
        int k = t - HM - WM;
        ws_logpe[k] = logf(p_levels[k] + EPSF);
    }
}

// Block = 8 model points of one row. 32 threads per point.
// Phase 1: each thread issues ALL its corner loads (20 full + up to 20 masked)
//          into registers BEFORE any use -> deep MLP. var is compile-time so
//          addresses are base + immediate (no per-slot division).
// Phase 2: thread (pt_local, k): binary-search nvalid + level, bilinear from
//          the per-point horizontally-interpolated column in LDS, lerp, store.
__global__ void __launch_bounds__(256)
fused_kernel(const float* __restrict__ u, const float* __restrict__ v,
             const float* __restrict__ w, const float* __restrict__ T,
             const float* __restrict__ q, const float* __restrict__ ps,
             const float* __restrict__ p_levels,
             const float* __restrict__ a_k, const float* __restrict__ b_k,
             const int* __restrict__ ws_iy, const float* __restrict__ ws_ty,
             const int* __restrict__ ws_ix, const float* __restrict__ ws_tx,
             const float* __restrict__ ws_logpe,
             float* __restrict__ out) {
    __shared__ float s_h[PTSB][5 * LL];   // 8 x 185; 185 % 32 = 25 -> conflict-benign
    __shared__ float s_psm[PTSB];
    __shared__ float s_plev[LL];
    __shared__ float s_logpe[LL];
    __shared__ float s_ak[KK];
    __shared__ float s_bk[KK];

    const int tid = threadIdx.x;
    if (tid < LL) {
        s_plev[tid]  = p_levels[tid];
        s_logpe[tid] = ws_logpe[tid];
    } else if (tid >= 64 && tid < 64 + KK) {
        s_ak[tid - 64] = a_k[tid - 64];
        s_bk[tid - 64] = b_k[tid - 64];
    }

    const int pt_local = tid >> 5;      // 0..7
    const int grp      = tid & 31;      // 0..31
    const int pt = blockIdx.x * PTSB + pt_local;
    const int y  = pt / WM;
    const int x  = pt - y * WM;

    const int   iy  = ws_iy[y];
    const float ty  = ws_ty[y];
    const int   ixp = ws_ix[x];
    const float tx  = ws_tx[x];
    const float omty = 1.0f - ty;
    const float omtx = 1.0f - tx;

    const size_t c00 = ((size_t)iy * WE + ixp) * LL;      // float index, row0 col0
    const size_t c10 = c00 + (size_t)WE * LL;             // row1 col0

    // ---- Phase 1a: issue ALL loads into registers (no intervening uses) ----
    float f00[5], f01[5], f10[5], f11[5];
    {
        const int l = grp;  // 0..31
#define LOADF(vv, sp) \
        f00[vv] = sp[c00 + l]; f01[vv] = sp[c00 + LL + l]; \
        f10[vv] = sp[c10 + l]; f11[vv] = sp[c10 + LL + l];
        LOADF(0, u) LOADF(1, v) LOADF(2, w) LOADF(3, T) LOADF(4, q)
#undef LOADF
    }
    float p00[5], p01[5], p10[5], p11[5];
    const bool part = (grp < (LL - 32));   // grp < 5 -> levels 32..36
    if (part) {
        const int l = 32 + grp;
#define LOADP(vv, sp) \
        p00[vv] = sp[c00 + l]; p01[vv] = sp[c00 + LL + l]; \
        p10[vv] = sp[c10 + l]; p11[vv] = sp[c10 + LL + l];
        LOADP(0, u) LOADP(1, v) LOADP(2, w) LOADP(3, T) LOADP(4, q)
#undef LOADP
    }

    // ---- per-point surface pressure (overlaps with loads above) ----
    if (grp == 0) {
        const size_t b00 = (size_t)iy * WE + ixp;
        const float s00 = ps[b00], s01 = ps[b00 + 1];
        const float s10 = ps[b00 + WE], s11 = ps[b00 + WE + 1];
        const float ps_m = omty * (omtx * s00 + tx * s01) + ty * (omtx * s10 + tx * s11);
        s_psm[pt_local] = ps_m;
        out[OFF2 + pt] = fminf(fmaxf(ps_m, 30000.0f), 110000.0f);
    }

    // ---- Phase 1b: consume loads -> LDS ----
#pragma unroll
    for (int vv = 0; vv < 5; vv++) {
        s_h[pt_local][vv * LL + grp] =
            omty * (omtx * f00[vv] + tx * f01[vv]) +
            ty   * (omtx * f10[vv] + tx * f11[vv]);
    }
    if (part) {
#pragma unroll
        for (int vv = 0; vv < 5; vv++) {
            s_h[pt_local][vv * LL + 32 + grp] =
                omty * (omtx * p00[vv] + tx * p01[vv]) +
                ty   * (omtx * p10[vv] + tx * p11[vv]);
        }
    }

    __syncthreads();

    // ---- Phase 2: vertical interp per (pt_local, k) ----
    const int k = grp;
    const float ps_m = s_psm[pt_local];

    // nvalid = upper_bound(p_levels, ps_m) via binary search (exact, no log)
    int lo = 0, hi = LL;
    while (lo < hi) {
        int m = (lo + hi) >> 1;
        if (s_plev[m] <= ps_m) lo = m + 1; else hi = m;
    }
    const int nvalid = lo;
    int maxi = nvalid - 2;
    if (maxi < 0) maxi = 0;

    const float pm = s_ak[k] + s_bk[k] * ps_m;
    out[OFF1 + (size_t)pt * KK + k] = pm;

    const float lpm = logf(pm + EPSF);
    lo = 0; hi = LL;
    while (lo < hi) {
        int m = (lo + hi) >> 1;
        if (s_logpe[m] <= lpm) lo = m + 1; else hi = m;
    }
    int i = lo - 1;
    if (i < 0) i = 0;
    if (i > maxi) i = maxi;
    const float t = (lpm - s_logpe[i]) / (s_logpe[i + 1] - s_logpe[i]);

    const bool invalid = (nvalid < 2);
    const size_t obase = (size_t)pt * (KK * 5) + k * 5;
#pragma unroll
    for (int var = 0; var < 5; var++) {
        const float g0 = s_h[pt_local][var * LL + i];
        const float g1 = s_h[pt_local][var * LL + i + 1];
        float o = g0 + t * (g1 - g0);
        if (invalid) o = 0.0f;                       // zero BEFORE clip (matches ref)
        if (var == 3) o = fminf(fmaxf(o, 150.0f), 350.0f);
        if (var == 4) o = fminf(fmaxf(o, 0.0f), 0.05f);
        out[obase + var] = o;
    }
}

extern "C" void kernel_launch(void* const* d_in, const int* in_sizes, int n_in,
                              void* d_out, int out_size, void* d_ws, size_t ws_size,
                              hipStream_t stream) {
    const float* u         = (const float*)d_in[0];
    const float* v         = (const float*)d_in[1];
    const float* w         = (const float*)d_in[2];
    const float* T         = (const float*)d_in[3];
    const float* q         = (const float*)d_in[4];
    const float* ps        = (const float*)d_in[5];
    const float* era5_lat  = (const float*)d_in[6];
    const float* era5_lon  = (const float*)d_in[7];
    const float* model_lat = (const float*)d_in[8];
    const float* model_lon = (const float*)d_in[9];
    const float* p_levels  = (const float*)d_in[10];
    const float* a_k       = (const float*)d_in[11];
    const float* b_k       = (const float*)d_in[12];

    float* wsf = (float*)d_ws;
    int*   ws_iy    = (int*)(wsf + WS_IY);
    float* ws_ty    = wsf + WS_TY;
    int*   ws_ix    = (int*)(wsf + WS_IX);
    float* ws_tx    = wsf + WS_TX;
    float* ws_logpe = wsf + WS_LOGPE;

    float* out = (float*)d_out;

    precompute_kernel<<<3, 256, 0, stream>>>(era5_lat, era5_lon, model_lat, model_lon,
                                             p_levels, ws_iy, ws_ty, ws_ix, ws_tx,
                                             ws_logpe);

    const int blocks = NPTS / PTSB;   // 8100
    fused_kernel<<<blocks, 256, 0, stream>>>(u, v, w, T, q, ps, p_levels, a_k, b_k,
                                             ws_iy, ws_ty, ws_ix, ws_tx, ws_logpe, out);
}